// Round 1
// baseline (57.949 us; speedup 1.0000x reference)
//
#include <hip/hip_runtime.h>
#include <hip/hip_bf16.h>

// Problem constants: B=2, N=512, C=256
// score[b,i,j] = sum_c relu(q[b,i,c]+k[b,j,c]) ; softmax over j ; out = attn@v @ Wp^T + bp

#define JS 16   // split-j factor for attention (key chunks of 32)

// ---------------- Kernel 1: fused QKV projection ----------------
// out[row,d] = sum_c A[row,c] * W[d,c]   (row = b*512+n, torch Linear no-bias)
// tile: 32 rows x 64 d, K-tile 32, 256 threads, reg tile 2x4
__global__ __launch_bounds__(256) void gemm_qkv(
    const float* __restrict__ x,
    const float* __restrict__ Wq, const float* __restrict__ Wk, const float* __restrict__ Wv,
    float* __restrict__ q, float* __restrict__ k, float* __restrict__ v)
{
    const int z = blockIdx.z;
    const float* W = (z == 0) ? Wq : ((z == 1) ? Wk : Wv);
    float* out = (z == 0) ? q : ((z == 1) ? k : v);
    const int row0 = blockIdx.x * 32;
    const int d0   = blockIdx.y * 64;

    __shared__ float AT[32][34];  // [c][r], stride even -> b64-aligned reads
    __shared__ float WT[32][68];  // [c][d], stride %4 -> b128-aligned reads

    const int tid = threadIdx.x;
    const int ty = tid >> 4, tx = tid & 15;

    float acc[2][4] = {};

    for (int c0 = 0; c0 < 256; c0 += 32) {
        {   // stage A: 32 rows x 32 c
            int r  = tid >> 3;
            int cg = (tid & 7) * 4;
            float4 a = *(const float4*)&x[(size_t)(row0 + r) * 256 + c0 + cg];
            AT[cg + 0][r] = a.x; AT[cg + 1][r] = a.y;
            AT[cg + 2][r] = a.z; AT[cg + 3][r] = a.w;
        }
        {   // stage W: 64 d x 32 c
            int d  = tid >> 2;
            int cq = (tid & 3) * 8;
            float4 w0 = *(const float4*)&W[(size_t)(d0 + d) * 256 + c0 + cq];
            float4 w1 = *(const float4*)&W[(size_t)(d0 + d) * 256 + c0 + cq + 4];
            WT[cq + 0][d] = w0.x; WT[cq + 1][d] = w0.y;
            WT[cq + 2][d] = w0.z; WT[cq + 3][d] = w0.w;
            WT[cq + 4][d] = w1.x; WT[cq + 5][d] = w1.y;
            WT[cq + 6][d] = w1.z; WT[cq + 7][d] = w1.w;
        }
        __syncthreads();
#pragma unroll
        for (int c = 0; c < 32; ++c) {
            float2 a = *(const float2*)&AT[c][ty * 2];
            float4 w = *(const float4*)&WT[c][tx * 4];
            acc[0][0] += a.x * w.x; acc[0][1] += a.x * w.y;
            acc[0][2] += a.x * w.z; acc[0][3] += a.x * w.w;
            acc[1][0] += a.y * w.x; acc[1][1] += a.y * w.y;
            acc[1][2] += a.y * w.z; acc[1][3] += a.y * w.w;
        }
        __syncthreads();
    }
#pragma unroll
    for (int rr = 0; rr < 2; ++rr) {
        float4 o = make_float4(acc[rr][0], acc[rr][1], acc[rr][2], acc[rr][3]);
        *(float4*)&out[(size_t)(row0 + ty * 2 + rr) * 256 + d0 + tx * 4] = o;
    }
}

// ---------------- Kernel 2: attention partial (split-j) ----------------
// Block handles (b, 32 queries, 32 keys): score tile -> local softmax -> p@v partial.
// Writes pacc[b,i,js,c] (unnormalized) and ml[b,i,js,{m,l}].
__global__ __launch_bounds__(256) void attn_partial(
    const float* __restrict__ q, const float* __restrict__ k, const float* __restrict__ v,
    float* __restrict__ pacc, float* __restrict__ ml)
{
    const int js = blockIdx.x;   // 0..15
    const int it = blockIdx.y;   // 0..15
    const int b  = blockIdx.z;   // 0..1
    const int i0 = it * 32, j0 = js * 32;

    const float* qb = q + (size_t)b * 512 * 256;
    const float* kb = k + (size_t)b * 512 * 256;
    const float* vb = v + (size_t)b * 512 * 256;

    __shared__ float qT[128][34];  // [c][i]
    __shared__ float kT[128][34];  // [c][j]
    __shared__ float pl[32][34];   // [i][j] probabilities

    const int tid = threadIdx.x;
    const int ty = tid >> 4, tx = tid & 15;

    float s[2][2] = {};

    for (int c0 = 0; c0 < 256; c0 += 128) {
        {   // stage q,k c-tile transposed
            int i  = tid >> 3;            // 0..31
            int cg = (tid & 7) * 16;      // 0..112
#pragma unroll
            for (int u = 0; u < 4; ++u) {
                float4 a = *(const float4*)&qb[(size_t)(i0 + i) * 256 + c0 + cg + u * 4];
                qT[cg + u * 4 + 0][i] = a.x; qT[cg + u * 4 + 1][i] = a.y;
                qT[cg + u * 4 + 2][i] = a.z; qT[cg + u * 4 + 3][i] = a.w;
                float4 bb = *(const float4*)&kb[(size_t)(j0 + i) * 256 + c0 + cg + u * 4];
                kT[cg + u * 4 + 0][i] = bb.x; kT[cg + u * 4 + 1][i] = bb.y;
                kT[cg + u * 4 + 2][i] = bb.z; kT[cg + u * 4 + 3][i] = bb.w;
            }
        }
        __syncthreads();
#pragma unroll 8
        for (int c = 0; c < 128; ++c) {
            float2 a  = *(const float2*)&qT[c][ty * 2];
            float2 bb = *(const float2*)&kT[c][tx * 2];
            s[0][0] += fmaxf(a.x + bb.x, 0.f);
            s[0][1] += fmaxf(a.x + bb.y, 0.f);
            s[1][0] += fmaxf(a.y + bb.x, 0.f);
            s[1][1] += fmaxf(a.y + bb.y, 0.f);
        }
        __syncthreads();
    }

    // local softmax over this block's 32 keys (rows spread over 16 tx lanes)
#pragma unroll
    for (int ii = 0; ii < 2; ++ii) {
        float mm = fmaxf(s[ii][0], s[ii][1]);
#pragma unroll
        for (int d = 1; d < 16; d <<= 1) mm = fmaxf(mm, __shfl_xor(mm, d));
        float p0 = __expf(s[ii][0] - mm);
        float p1 = __expf(s[ii][1] - mm);
        float ll = p0 + p1;
#pragma unroll
        for (int d = 1; d < 16; d <<= 1) ll += __shfl_xor(ll, d);
        *(float2*)&pl[ty * 2 + ii][tx * 2] = make_float2(p0, p1);
        if (tx == 0) {
            size_t idx = ((size_t)(b * 512 + i0 + ty * 2 + ii) * JS + js) * 2;
            ml[idx]     = mm;
            ml[idx + 1] = ll;
        }
    }
    __syncthreads();

    // PV partial: remap threads -> (wave iu owns 8 rows, lane cu owns 4 c's)
    const int cu = tid & 63, iu = tid >> 6;
    float acc[8][4] = {};
    for (int j = 0; j < 32; ++j) {
        float4 vv = *(const float4*)&vb[(size_t)(j0 + j) * 256 + cu * 4];
#pragma unroll
        for (int r = 0; r < 8; ++r) {
            float p = pl[iu * 8 + r][j];
            acc[r][0] += p * vv.x; acc[r][1] += p * vv.y;
            acc[r][2] += p * vv.z; acc[r][3] += p * vv.w;
        }
    }
#pragma unroll
    for (int r = 0; r < 8; ++r) {
        size_t idx = ((size_t)(b * 512 + i0 + iu * 8 + r) * JS + js) * 256 + cu * 4;
        *(float4*)&pacc[idx] = make_float4(acc[r][0], acc[r][1], acc[r][2], acc[r][3]);
    }
}

// ---------------- Kernel 3: combine split-j partials ----------------
__global__ __launch_bounds__(256) void combine(
    const float* __restrict__ pacc, const float* __restrict__ ml, float* __restrict__ O)
{
    const int bi = blockIdx.x;    // 0..1023 (b*512+i)
    const int c  = threadIdx.x;   // 0..255
    float mv[JS], lv[JS];
    float M = -1e30f;
#pragma unroll
    for (int s = 0; s < JS; ++s) {
        mv[s] = ml[((size_t)bi * JS + s) * 2];
        lv[s] = ml[((size_t)bi * JS + s) * 2 + 1];
        M = fmaxf(M, mv[s]);
    }
    float L = 0.f, o = 0.f;
#pragma unroll
    for (int s = 0; s < JS; ++s) {
        float w = __expf(mv[s] - M);
        L += w * lv[s];
        o += w * pacc[((size_t)bi * JS + s) * 256 + c];
    }
    O[(size_t)bi * 256 + c] = o / L;
}

// ---------------- Kernel 4: final projection + bias ----------------
__global__ __launch_bounds__(256) void gemm_bias(
    const float* __restrict__ A, const float* __restrict__ W,
    const float* __restrict__ bias, float* __restrict__ out)
{
    const int row0 = blockIdx.x * 32;
    const int d0   = blockIdx.y * 64;

    __shared__ float AT[32][34];
    __shared__ float WT[32][68];

    const int tid = threadIdx.x;
    const int ty = tid >> 4, tx = tid & 15;

    float acc[2][4] = {};

    for (int c0 = 0; c0 < 256; c0 += 32) {
        {
            int r  = tid >> 3;
            int cg = (tid & 7) * 4;
            float4 a = *(const float4*)&A[(size_t)(row0 + r) * 256 + c0 + cg];
            AT[cg + 0][r] = a.x; AT[cg + 1][r] = a.y;
            AT[cg + 2][r] = a.z; AT[cg + 3][r] = a.w;
        }
        {
            int d  = tid >> 2;
            int cq = (tid & 3) * 8;
            float4 w0 = *(const float4*)&W[(size_t)(d0 + d) * 256 + c0 + cq];
            float4 w1 = *(const float4*)&W[(size_t)(d0 + d) * 256 + c0 + cq + 4];
            WT[cq + 0][d] = w0.x; WT[cq + 1][d] = w0.y;
            WT[cq + 2][d] = w0.z; WT[cq + 3][d] = w0.w;
            WT[cq + 4][d] = w1.x; WT[cq + 5][d] = w1.y;
            WT[cq + 6][d] = w1.z; WT[cq + 7][d] = w1.w;
        }
        __syncthreads();
#pragma unroll
        for (int c = 0; c < 32; ++c) {
            float2 a = *(const float2*)&AT[c][ty * 2];
            float4 w = *(const float4*)&WT[c][tx * 4];
            acc[0][0] += a.x * w.x; acc[0][1] += a.x * w.y;
            acc[0][2] += a.x * w.z; acc[0][3] += a.x * w.w;
            acc[1][0] += a.y * w.x; acc[1][1] += a.y * w.y;
            acc[1][2] += a.y * w.z; acc[1][3] += a.y * w.w;
        }
        __syncthreads();
    }
    float4 bb = *(const float4*)&bias[d0 + tx * 4];
#pragma unroll
    for (int rr = 0; rr < 2; ++rr) {
        float4 o = make_float4(acc[rr][0] + bb.x, acc[rr][1] + bb.y,
                               acc[rr][2] + bb.z, acc[rr][3] + bb.w);
        *(float4*)&out[(size_t)(row0 + ty * 2 + rr) * 256 + d0 + tx * 4] = o;
    }
}

extern "C" void kernel_launch(void* const* d_in, const int* in_sizes, int n_in,
                              void* d_out, int out_size, void* d_ws, size_t ws_size,
                              hipStream_t stream) {
    const float* x  = (const float*)d_in[0];
    const float* Wq = (const float*)d_in[1];
    const float* Wk = (const float*)d_in[2];
    const float* Wv = (const float*)d_in[3];
    const float* Wp = (const float*)d_in[4];
    const float* bp = (const float*)d_in[5];
    float* out = (float*)d_out;

    float* ws = (float*)d_ws;
    const size_t BNC = (size_t)2 * 512 * 256;     // 262144
    float* q    = ws;
    float* k    = q + BNC;
    float* v    = k + BNC;
    float* O    = v + BNC;
    float* pacc = O + BNC;                        // 2*512*16*256 floats = 16 MB
    float* mlb  = pacc + (size_t)2 * 512 * JS * 256;
    // total ws use ~ 21 MB

    gemm_qkv<<<dim3(32, 4, 3), 256, 0, stream>>>(x, Wq, Wk, Wv, q, k, v);
    attn_partial<<<dim3(16, 16, 2), 256, 0, stream>>>(q, k, v, pacc, mlb);
    combine<<<dim3(1024), 256, 0, stream>>>(pacc, mlb, O);
    gemm_bias<<<dim3(32, 4), 256, 0, stream>>>(O, Wp, bp, out);
}